// Round 1
// baseline (706.992 us; speedup 1.0000x reference)
//
#include <hip/hip_runtime.h>
#include <cstddef>

#define S_LEN 2048
#define D_DIM 512
#define NHEAD 4
#define DHEAD 128
#define BH_CNT 16
#define SCALE_QK 0.08838834764831845f

__device__ __forceinline__ void fma4(float4& a, float s, const float4& b) {
  a.x = fmaf(s, b.x, a.x);
  a.y = fmaf(s, b.y, a.y);
  a.z = fmaf(s, b.z, a.z);
  a.w = fmaf(s, b.w, a.w);
}

// ---------------- Kernel 1: gate preactivations ----------------
// i_pre[b,h,s] = dot(concat(q,k,v)[b,s,:], Wi[h,:]) + bi[h]; same for f.
// One wave per (b,s); lanes stride the 1536 features.
__global__ __launch_bounds__(256) void gate_kernel(
    const float* __restrict__ q, const float* __restrict__ k, const float* __restrict__ v,
    const float* __restrict__ Wi, const float* __restrict__ bi,
    const float* __restrict__ Wf, const float* __restrict__ bf,
    float* __restrict__ ipre, float* __restrict__ fpre)
{
  const int wave = threadIdx.x >> 6;
  const int lane = threadIdx.x & 63;
  const int pos  = blockIdx.x * 4 + wave;           // 0..B*S-1
  const int b = pos >> 11;
  const int s = pos & 2047;
  const float* qp = q + (size_t)pos * D_DIM;
  const float* kp = k + (size_t)pos * D_DIM;
  const float* vp = v + (size_t)pos * D_DIM;

  float acc[8] = {0.f,0.f,0.f,0.f,0.f,0.f,0.f,0.f};
  #pragma unroll
  for (int j = 0; j < 24; ++j) {
    int e = lane + (j << 6);
    float x;
    if (e < 512)       x = qp[e];
    else if (e < 1024) x = kp[e - 512];
    else               x = vp[e - 1024];
    #pragma unroll
    for (int h = 0; h < 4; ++h) {
      acc[h]     = fmaf(x, Wi[h * 1536 + e], acc[h]);
      acc[4 + h] = fmaf(x, Wf[h * 1536 + e], acc[4 + h]);
    }
  }
  #pragma unroll
  for (int off = 32; off > 0; off >>= 1) {
    #pragma unroll
    for (int a = 0; a < 8; ++a) acc[a] += __shfl_down(acc[a], off);
  }
  if (lane == 0) {
    #pragma unroll
    for (int h = 0; h < 4; ++h) {
      ipre[(size_t)(b * 4 + h) * S_LEN + s] = acc[h] + bi[h];
      fpre[(size_t)(b * 4 + h) * S_LEN + s] = acc[4 + h] + bf[h];
    }
  }
}

// ---------------- Kernel 2: per-(b,h) scans ----------------
// bcum = cumsum(log_sigmoid(f_pre)); g = i_pre - bcum; M = cummax(g).
__global__ __launch_bounds__(256) void scan_kernel(
    const float* __restrict__ ipre, const float* __restrict__ fpre,
    float* __restrict__ g_out, float* __restrict__ M_out, float* __restrict__ bsum_out)
{
  __shared__ float A[2048];
  __shared__ float Bf[2048];
  const int bh  = blockIdx.x;
  const int tid = threadIdx.x;
  const float* fp = fpre + (size_t)bh * S_LEN;
  const float* ip = ipre + (size_t)bh * S_LEN;

  for (int i = tid; i < 2048; i += 256) {
    float x = fp[i];
    A[i] = fminf(x, 0.f) - log1pf(expf(-fabsf(x)));
  }
  __syncthreads();
  float* src = A; float* dst = Bf;
  for (int off = 1; off < 2048; off <<= 1) {
    for (int i = tid; i < 2048; i += 256)
      dst[i] = (i >= off) ? (src[i] + src[i - off]) : src[i];
    __syncthreads();
    float* t = src; src = dst; dst = t;
  }
  // src = bcum
  for (int i = tid; i < 2048; i += 256) {
    float bs = src[i];
    bsum_out[(size_t)bh * S_LEN + i] = bs;
    dst[i] = ip[i] - bs;                       // g
  }
  __syncthreads();
  for (int i = tid; i < 2048; i += 256)
    g_out[(size_t)bh * S_LEN + i] = dst[i];
  { float* t = src; src = dst; dst = t; }      // src = g
  for (int off = 1; off < 2048; off <<= 1) {
    for (int i = tid; i < 2048; i += 256)
      dst[i] = (i >= off) ? fmaxf(src[i], src[i - off]) : src[i];
    __syncthreads();
    float* t = src; src = dst; dst = t;
  }
  for (int i = tid; i < 2048; i += 256)
    M_out[(size_t)bh * S_LEN + i] = src[i];
}

// ---------------- Kernel 3: causal weighted attention + LN ----------------
// 64x64 tiles. C[t,s] = (q.k/sqrt(DH)) * exp(g[s]-M[t]);
// n = max(|sum_s C|, exp(-(bcum[t]+M[t]))); h = (C @ V)/(n+eps); per-head LN.
__global__ __launch_bounds__(256, 1) void attn_kernel(
    const float* __restrict__ q, const float* __restrict__ k, const float* __restrict__ v,
    const float* __restrict__ g_arr, const float* __restrict__ M_arr, const float* __restrict__ bs_arr,
    const float* __restrict__ ln_w, const float* __restrict__ ln_b,
    float* __restrict__ out)
{
  const int qt  = (int)gridDim.x - 1 - (int)blockIdx.x;  // heavy tiles first
  const int bh  = blockIdx.y;
  const int b   = bh >> 2, hh = bh & 3;
  const int t0  = qt * 64;
  const int tid = threadIdx.x;
  const int tx  = tid & 15, ty = tid >> 4;

  __shared__ float Qs[128 * 68];   // Q transposed: [kk][r], stride 68
  __shared__ float KV[128 * 68];   // K phase: [kk][c] stride 68; V phase: [c][d] stride 132
  __shared__ float Cs[64 * 68];    // C transposed: [c][r], stride 68
  __shared__ float red[64 * 17];   // row reductions

  const int um = tid >> 3;   // 0..31
  const int uu = tid & 7;    // 0..7

  // ---- stage Q (transposed) ----
  const float* qb = q + (size_t)(b * S_LEN + t0) * D_DIM + hh * DHEAD;
  #pragma unroll
  for (int i = 0; i < 8; ++i) {
    int r  = um + 32 * (i & 1);
    int kk = (uu + 8 * (i >> 1)) << 2;
    float4 val = *(const float4*)(qb + (size_t)r * D_DIM + kk);
    Qs[(kk + 0) * 68 + r] = val.x;
    Qs[(kk + 1) * 68 + r] = val.y;
    Qs[(kk + 2) * 68 + r] = val.z;
    Qs[(kk + 3) * 68 + r] = val.w;
  }

  float Mr[4], em[4];
  #pragma unroll
  for (int i = 0; i < 4; ++i) {
    int t = t0 + ty * 4 + i;
    float Mv = M_arr[(size_t)bh * S_LEN + t];
    Mr[i] = Mv;
    em[i] = expf(-(bs_arr[(size_t)bh * S_LEN + t] + Mv));
  }

  float4 accA[4], accB[4];
  #pragma unroll
  for (int i = 0; i < 4; ++i) { accA[i] = make_float4(0,0,0,0); accB[i] = make_float4(0,0,0,0); }
  float rowsum[4] = {0.f, 0.f, 0.f, 0.f};

  const float* kb = k + (size_t)(b * S_LEN) * D_DIM + hh * DHEAD;
  const float* vb = v + (size_t)(b * S_LEN) * D_DIM + hh * DHEAD;
  const float* gb = g_arr + (size_t)bh * S_LEN;

  float4 kreg[8], vreg[8];
  float  greg[4];

  // prologue loads for kt = 0
  #pragma unroll
  for (int i = 0; i < 8; ++i) {
    int c  = um + 32 * (i & 1);
    int kk = (uu + 8 * (i >> 1)) << 2;
    kreg[i] = *(const float4*)(kb + (size_t)c * D_DIM + kk);
  }
  #pragma unroll
  for (int i = 0; i < 8; ++i) {
    int f = tid + i * 256;
    int c = f >> 5, dq = (f & 31) << 2;
    vreg[i] = *(const float4*)(vb + (size_t)c * D_DIM + dq);
  }
  #pragma unroll
  for (int j = 0; j < 4; ++j) greg[j] = gb[tx * 4 + j];

  for (int kt = 0; kt <= qt; ++kt) {
    __syncthreads();                       // prev PV done: KV reusable
    // K regs -> LDS (transposed)
    #pragma unroll
    for (int i = 0; i < 8; ++i) {
      int c  = um + 32 * (i & 1);
      int kk = (uu + 8 * (i >> 1)) << 2;
      KV[(kk + 0) * 68 + c] = kreg[i].x;
      KV[(kk + 1) * 68 + c] = kreg[i].y;
      KV[(kk + 2) * 68 + c] = kreg[i].z;
      KV[(kk + 3) * 68 + c] = kreg[i].w;
    }
    __syncthreads();                       // K visible
    if (kt < qt) {                         // prefetch next K into regs
      const float* kbn = kb + (size_t)(kt + 1) * 64 * D_DIM;
      #pragma unroll
      for (int i = 0; i < 8; ++i) {
        int c  = um + 32 * (i & 1);
        int kk = (uu + 8 * (i >> 1)) << 2;
        kreg[i] = *(const float4*)(kbn + (size_t)c * D_DIM + kk);
      }
    }
    // ---- QK^T: 4x4 per thread ----
    float4 accq[4];
    #pragma unroll
    for (int i = 0; i < 4; ++i) accq[i] = make_float4(0,0,0,0);
    #pragma unroll 8
    for (int kk = 0; kk < 128; ++kk) {
      const float4 qv = *(const float4*)&Qs[kk * 68 + (ty << 2)];
      const float4 kv = *(const float4*)&KV[kk * 68 + (tx << 2)];
      fma4(accq[0], qv.x, kv);
      fma4(accq[1], qv.y, kv);
      fma4(accq[2], qv.z, kv);
      fma4(accq[3], qv.w, kv);
    }
    // ---- C transform ----
    float cm[4][4];
    #pragma unroll
    for (int i = 0; i < 4; ++i) {
      cm[i][0] = accq[i].x * SCALE_QK * __expf(greg[0] - Mr[i]);
      cm[i][1] = accq[i].y * SCALE_QK * __expf(greg[1] - Mr[i]);
      cm[i][2] = accq[i].z * SCALE_QK * __expf(greg[2] - Mr[i]);
      cm[i][3] = accq[i].w * SCALE_QK * __expf(greg[3] - Mr[i]);
    }
    if (kt == qt) {
      #pragma unroll
      for (int i = 0; i < 4; ++i)
        #pragma unroll
        for (int j = 0; j < 4; ++j)
          if ((tx << 2) + j > (ty << 2) + i) cm[i][j] = 0.f;
    }
    #pragma unroll
    for (int i = 0; i < 4; ++i)
      rowsum[i] += cm[i][0] + cm[i][1] + cm[i][2] + cm[i][3];

    __syncthreads();                       // K reads done: KV reusable for V
    // V regs -> LDS (natural layout, stride 132)
    #pragma unroll
    for (int i = 0; i < 8; ++i) {
      int f = tid + i * 256;
      int c = f >> 5, dq = (f & 31) << 2;
      *(float4*)&KV[c * 132 + dq] = vreg[i];
    }
    // C -> LDS (transposed [c][r])
    #pragma unroll
    for (int j = 0; j < 4; ++j) {
      float4 cv = make_float4(cm[0][j], cm[1][j], cm[2][j], cm[3][j]);
      *(float4*)&Cs[(tx * 4 + j) * 68 + (ty << 2)] = cv;
    }
    if (kt < qt) {                         // prefetch next V, g into regs
      const float* vbn = vb + (size_t)(kt + 1) * 64 * D_DIM;
      #pragma unroll
      for (int i = 0; i < 8; ++i) {
        int f = tid + i * 256;
        int c = f >> 5, dq = (f & 31) << 2;
        vreg[i] = *(const float4*)(vbn + (size_t)c * D_DIM + dq);
      }
      #pragma unroll
      for (int j = 0; j < 4; ++j) greg[j] = gb[(kt + 1) * 64 + tx * 4 + j];
    }
    __syncthreads();                       // V + Cs visible
    // ---- PV: 4 rows x 8 cols per thread ----
    #pragma unroll 4
    for (int c = 0; c < 64; ++c) {
      const float4 cv  = *(const float4*)&Cs[c * 68 + (ty << 2)];
      const float4 va  = *(const float4*)&KV[c * 132 + (tx << 2)];
      const float4 vb4 = *(const float4*)&KV[c * 132 + 64 + (tx << 2)];
      fma4(accA[0], cv.x, va);  fma4(accB[0], cv.x, vb4);
      fma4(accA[1], cv.y, va);  fma4(accB[1], cv.y, vb4);
      fma4(accA[2], cv.z, va);  fma4(accB[2], cv.z, vb4);
      fma4(accA[3], cv.w, va);  fma4(accB[3], cv.w, vb4);
    }
  }

  // ---- rowsum reduction -> n -> 1/(n+eps) ----
  #pragma unroll
  for (int i = 0; i < 4; ++i) red[(ty * 4 + i) * 17 + tx] = rowsum[i];
  __syncthreads();
  float invn[4];
  #pragma unroll
  for (int i = 0; i < 4; ++i) {
    float tot = 0.f;
    #pragma unroll
    for (int t2 = 0; t2 < 16; ++t2) tot += red[(ty * 4 + i) * 17 + t2];
    float nn = fmaxf(fabsf(tot), em[i]);
    invn[i] = 1.f / (nn + 5e-5f);
  }
  __syncthreads();

  // h = accv * invn
  #pragma unroll
  for (int i = 0; i < 4; ++i) {
    accA[i].x *= invn[i]; accA[i].y *= invn[i]; accA[i].z *= invn[i]; accA[i].w *= invn[i];
    accB[i].x *= invn[i]; accB[i].y *= invn[i]; accB[i].z *= invn[i]; accB[i].w *= invn[i];
  }
  // mean
  #pragma unroll
  for (int i = 0; i < 4; ++i) {
    float s1 = accA[i].x + accA[i].y + accA[i].z + accA[i].w
             + accB[i].x + accB[i].y + accB[i].z + accB[i].w;
    red[(ty * 4 + i) * 17 + tx] = s1;
  }
  __syncthreads();
  float mu[4];
  #pragma unroll
  for (int i = 0; i < 4; ++i) {
    float tot = 0.f;
    #pragma unroll
    for (int t2 = 0; t2 < 16; ++t2) tot += red[(ty * 4 + i) * 17 + t2];
    mu[i] = tot * 0.0078125f;
  }
  __syncthreads();
  // var
  #pragma unroll
  for (int i = 0; i < 4; ++i) {
    float s2 = accA[i].x * accA[i].x + accA[i].y * accA[i].y + accA[i].z * accA[i].z + accA[i].w * accA[i].w
             + accB[i].x * accB[i].x + accB[i].y * accB[i].y + accB[i].z * accB[i].z + accB[i].w * accB[i].w;
    red[(ty * 4 + i) * 17 + tx] = s2;
  }
  __syncthreads();
  float rstd[4];
  #pragma unroll
  for (int i = 0; i < 4; ++i) {
    float tot = 0.f;
    #pragma unroll
    for (int t2 = 0; t2 < 16; ++t2) tot += red[(ty * 4 + i) * 17 + t2];
    float var = tot * 0.0078125f - mu[i] * mu[i];
    rstd[i] = rsqrtf(var + 1e-3f);
  }

  const float* lwp = ln_w + hh * DHEAD;
  const float* lbp = ln_b + hh * DHEAD;
  const float4 wv1 = *(const float4*)(lwp + tx * 4);
  const float4 wv2 = *(const float4*)(lwp + 64 + tx * 4);
  const float4 bv1 = *(const float4*)(lbp + tx * 4);
  const float4 bv2 = *(const float4*)(lbp + 64 + tx * 4);

  #pragma unroll
  for (int i = 0; i < 4; ++i) {
    float4 o1, o2;
    o1.x = (accA[i].x - mu[i]) * rstd[i] * (1.f + wv1.x) + bv1.x;
    o1.y = (accA[i].y - mu[i]) * rstd[i] * (1.f + wv1.y) + bv1.y;
    o1.z = (accA[i].z - mu[i]) * rstd[i] * (1.f + wv1.z) + bv1.z;
    o1.w = (accA[i].w - mu[i]) * rstd[i] * (1.f + wv1.w) + bv1.w;
    o2.x = (accB[i].x - mu[i]) * rstd[i] * (1.f + wv2.x) + bv2.x;
    o2.y = (accB[i].y - mu[i]) * rstd[i] * (1.f + wv2.y) + bv2.y;
    o2.z = (accB[i].z - mu[i]) * rstd[i] * (1.f + wv2.z) + bv2.z;
    o2.w = (accB[i].w - mu[i]) * rstd[i] * (1.f + wv2.w) + bv2.w;
    float* orow = out + (size_t)(b * S_LEN + t0 + ty * 4 + i) * D_DIM + hh * DHEAD;
    *(float4*)(orow + tx * 4) = o1;
    *(float4*)(orow + 64 + tx * 4) = o2;
  }
}

extern "C" void kernel_launch(void* const* d_in, const int* in_sizes, int n_in,
                              void* d_out, int out_size, void* d_ws, size_t ws_size,
                              hipStream_t stream) {
  const float* q    = (const float*)d_in[0];
  const float* k    = (const float*)d_in[1];
  const float* v    = (const float*)d_in[2];
  const float* Wi   = (const float*)d_in[3];
  const float* bi   = (const float*)d_in[4];
  const float* Wf   = (const float*)d_in[5];
  const float* bf   = (const float*)d_in[6];
  const float* ln_w = (const float*)d_in[7];
  const float* ln_b = (const float*)d_in[8];

  float* ws   = (float*)d_ws;
  float* ipre = ws;
  float* fpre = ipre + (size_t)BH_CNT * S_LEN;
  float* garr = fpre + (size_t)BH_CNT * S_LEN;
  float* Marr = garr + (size_t)BH_CNT * S_LEN;
  float* bsum = Marr + (size_t)BH_CNT * S_LEN;

  gate_kernel<<<2048, 256, 0, stream>>>(q, k, v, Wi, bi, Wf, bf, ipre, fpre);
  scan_kernel<<<16, 256, 0, stream>>>(ipre, fpre, garr, Marr, bsum);
  attn_kernel<<<dim3(32, 16), 256, 0, stream>>>(q, k, v, garr, Marr, bsum, ln_w, ln_b,
                                                (float*)d_out);
}

// Round 3
// 111.059 us; speedup vs baseline: 6.3659x; 6.3659x over previous
//
#include <hip/hip_runtime.h>
#include <cstddef>
#include <cstdint>

#define S_LEN 2048
#define D_DIM 512
#define NHEAD 4
#define DHEAD 128
#define BH_CNT 16
#define SCALE_QK 0.08838834764831845f

typedef _Float16 f16;
typedef _Float16 f16x8 __attribute__((ext_vector_type(8)));
typedef float f32x16 __attribute__((ext_vector_type(16)));

#define AS1 __attribute__((address_space(1)))
#define AS3 __attribute__((address_space(3)))

__device__ __forceinline__ unsigned pkh(float a, float b) {
  auto r = __builtin_amdgcn_cvt_pkrtz(a, b);   // __fp16 ext_vector_type(2)
  return __builtin_bit_cast(unsigned, r);
}

// ---------------- Kernel 1: gate preactivations ----------------
__global__ __launch_bounds__(256) void gate_kernel(
    const float* __restrict__ q, const float* __restrict__ k, const float* __restrict__ v,
    const float* __restrict__ Wi, const float* __restrict__ bi,
    const float* __restrict__ Wf, const float* __restrict__ bf,
    float* __restrict__ ipre, float* __restrict__ fpre)
{
  const int wave = threadIdx.x >> 6;
  const int lane = threadIdx.x & 63;
  const int pos  = blockIdx.x * 4 + wave;
  const int b = pos >> 11;
  const int s = pos & 2047;
  const float* qp = q + (size_t)pos * D_DIM;
  const float* kp = k + (size_t)pos * D_DIM;
  const float* vp = v + (size_t)pos * D_DIM;

  float acc[8] = {0.f,0.f,0.f,0.f,0.f,0.f,0.f,0.f};
  #pragma unroll
  for (int j = 0; j < 24; ++j) {
    int e = lane + (j << 6);
    float x;
    if (e < 512)       x = qp[e];
    else if (e < 1024) x = kp[e - 512];
    else               x = vp[e - 1024];
    #pragma unroll
    for (int h = 0; h < 4; ++h) {
      acc[h]     = fmaf(x, Wi[h * 1536 + e], acc[h]);
      acc[4 + h] = fmaf(x, Wf[h * 1536 + e], acc[4 + h]);
    }
  }
  #pragma unroll
  for (int off = 32; off > 0; off >>= 1) {
    #pragma unroll
    for (int a = 0; a < 8; ++a) acc[a] += __shfl_down(acc[a], off);
  }
  if (lane == 0) {
    #pragma unroll
    for (int h = 0; h < 4; ++h) {
      ipre[(size_t)(b * 4 + h) * S_LEN + s] = acc[h] + bi[h];
      fpre[(size_t)(b * 4 + h) * S_LEN + s] = acc[4 + h] + bf[h];
    }
  }
}

// ---------------- Kernel 2: scans + per-128-tile g max ----------------
__global__ __launch_bounds__(256) void scan_kernel(
    const float* __restrict__ ipre, const float* __restrict__ fpre,
    float* __restrict__ g_out, float* __restrict__ M_out,
    float* __restrict__ bsum_out, float* __restrict__ Gt_out)
{
  __shared__ float A[2048];
  __shared__ float Bf[2048];
  const int bh  = blockIdx.x;
  const int tid = threadIdx.x;
  const float* fp = fpre + (size_t)bh * S_LEN;
  const float* ip = ipre + (size_t)bh * S_LEN;

  for (int i = tid; i < 2048; i += 256) {
    float x = fp[i];
    A[i] = fminf(x, 0.f) - log1pf(expf(-fabsf(x)));
  }
  __syncthreads();
  float* src = A; float* dst = Bf;
  for (int off = 1; off < 2048; off <<= 1) {
    for (int i = tid; i < 2048; i += 256)
      dst[i] = (i >= off) ? (src[i] + src[i - off]) : src[i];
    __syncthreads();
    float* t = src; src = dst; dst = t;
  }
  // src = bcum
  for (int i = tid; i < 2048; i += 256) {
    float bs = src[i];
    bsum_out[(size_t)bh * S_LEN + i] = bs;
    float g = ip[i] - bs;
    g_out[(size_t)bh * S_LEN + i] = g;
    dst[i] = g;
  }
  __syncthreads();
  { float* t = src; src = dst; dst = t; }      // src = g
  if (tid < 16) {
    float m = -3.0e38f;
    for (int i = 0; i < 128; ++i) m = fmaxf(m, src[tid * 128 + i]);
    Gt_out[bh * 16 + tid] = m;
  }
  __syncthreads();
  for (int off = 1; off < 2048; off <<= 1) {
    for (int i = tid; i < 2048; i += 256)
      dst[i] = (i >= off) ? fmaxf(src[i], src[i - off]) : src[i];
    __syncthreads();
    float* t = src; src = dst; dst = t;
  }
  for (int i = tid; i < 2048; i += 256)
    M_out[(size_t)bh * S_LEN + i] = src[i];
}

// ---------------- Kernel 3: fp16 conversion into MFMA-ready swizzled layouts ----
// qhat/khat tile (bh,it): row s(128) x 256B, elem d at byte (2d)^((s&15)<<4)
// vT tile: row d(128) x 256B, elem s at byte (2s)^((d&15)<<4)
__global__ __launch_bounds__(256) void convert_kernel(
    const float* __restrict__ q, const float* __restrict__ k, const float* __restrict__ v,
    const float* __restrict__ g_arr, const float* __restrict__ Gt_arr,
    char* __restrict__ qhat, char* __restrict__ khat, char* __restrict__ vT)
{
  const int it = blockIdx.x;
  const int bh = blockIdx.y;
  const int b = bh >> 2, hh = bh & 3;
  const int tid = threadIdx.x;
  const size_t tb = (size_t)(bh * 16 + it) * 32768;
  const float Gtv = Gt_arr[bh * 16 + it];
  const int rl = tid & 31, rg = tid >> 5;
  for (int j = 0; j < 16; ++j) {
    const int s = rg + 8 * j;
    const int sg = it * 128 + s;
    const float* qrow = q + ((size_t)(b * S_LEN + sg)) * D_DIM + hh * DHEAD;
    const float* krow = k + ((size_t)(b * S_LEN + sg)) * D_DIM + hh * DHEAD;
    float4 qv = *(const float4*)(qrow + rl * 4);
    float4 kv = *(const float4*)(krow + rl * 4);
    float cf = __expf(g_arr[(size_t)bh * S_LEN + sg] - Gtv);
    uint2 qp, kp;
    qp.x = pkh(qv.x * SCALE_QK, qv.y * SCALE_QK);
    qp.y = pkh(qv.z * SCALE_QK, qv.w * SCALE_QK);
    kp.x = pkh(kv.x * cf, kv.y * cf);
    kp.y = pkh(kv.z * cf, kv.w * cf);
    const int off = (rl * 8) ^ ((s & 15) << 4);
    *(uint2*)(qhat + tb + s * 256 + off) = qp;
    *(uint2*)(khat + tb + s * 256 + off) = kp;
  }
  const int d = tid & 127, oc = tid >> 7;
  for (int j = 0; j < 8; ++j) {
    const int s0 = (oc + 2 * j) * 8;
    float vv[8];
    #pragma unroll
    for (int i = 0; i < 8; ++i)
      vv[i] = v[((size_t)(b * S_LEN + it * 128 + s0 + i)) * D_DIM + hh * DHEAD + d];
    uint4 pk4;
    pk4.x = pkh(vv[0], vv[1]); pk4.y = pkh(vv[2], vv[3]);
    pk4.z = pkh(vv[4], vv[5]); pk4.w = pkh(vv[6], vv[7]);
    const int off = (s0 * 2) ^ ((d & 15) << 4);
    *(uint4*)(vT + tb + d * 256 + off) = pk4;
  }
}

// ---------------- Kernel 4: MFMA attention ----------------
// S = K_hat(128s x 128d) * Qhat^T(128d x 128t) via mfma_32x32x16_f16
// P = S*rf (mask diag), reshaped in-register to PV B-frags
// h^T(128d x 128t) += V^T * P, accumulated over kt tiles; then n, LN, store.
__global__ __launch_bounds__(256) void attn_kernel(
    const char* __restrict__ qhat, const char* __restrict__ khat, const char* __restrict__ vT,
    const float* __restrict__ M_arr, const float* __restrict__ bs_arr,
    const float* __restrict__ Gt_arr,
    const float* __restrict__ ln_w, const float* __restrict__ ln_b,
    float* __restrict__ out)
{
  __shared__ __align__(16) char smem[131072];   // buf0: K@0 V@32768 ; buf1: K@65536 V@98304
  const int qt = blockIdx.x, bh = blockIdx.y;
  const int b = bh >> 2, hh = bh & 3;
  const int tid = threadIdx.x;
  const int w = tid >> 6, lane = tid & 63, lo = lane & 31, hi = lane >> 5;
  const int tl = 32 * w + lo;            // local t (0..127)
  const int tg = qt * 128 + tl;          // global t
  const int swz = (lo & 15) << 4;

  const char* gq = qhat + (size_t)(bh * 16 + qt) * 32768;
  const char* gk = khat + (size_t)(bh * 16) * 32768;
  const char* gv = vT   + (size_t)(bh * 16) * 32768;

  const float Mt = M_arr[(size_t)bh * S_LEN + tg];
  const float em = __expf(-(bs_arr[(size_t)bh * S_LEN + tg] + Mt));
  const float M0 = M_arr[(size_t)bh * S_LEN + qt * 128];

  int kts = 0;
  while (kts < qt && Gt_arr[bh * 16 + kts] < M0 - 25.f) ++kts;

  // stage Q tile into buf1-K region, read fragments into regs
  #pragma unroll
  for (int i = 0; i < 8; ++i) {
    int off = (i * 256 + tid) * 16;
    __builtin_amdgcn_global_load_lds((const AS1 void*)(gq + off),
                                     (AS3 void*)(smem + 65536 + off), 16, 0, 0);
  }
  asm volatile("s_waitcnt vmcnt(0)" ::: "memory");
  __syncthreads();
  f16x8 qf[8];
  #pragma unroll
  for (int ks = 0; ks < 8; ++ks)
    qf[ks] = *(const f16x8*)(smem + 65536 + tl * 256 + ((ks * 32 + hi * 16) ^ swz));
  __syncthreads();   // all waves done reading Q before buf1 can be overwritten

  f32x16 h[4] = {{}, {}, {}, {}};
  float rowsum = 0.f;

  // prologue: stage tile kts into buf0
  {
    const char* gkt = gk + (size_t)kts * 32768;
    const char* gvt = gv + (size_t)kts * 32768;
    #pragma unroll
    for (int i = 0; i < 8; ++i) {
      int off = (i * 256 + tid) * 16;
      __builtin_amdgcn_global_load_lds((const AS1 void*)(gkt + off), (AS3 void*)(smem + off), 16, 0, 0);
      __builtin_amdgcn_global_load_lds((const AS1 void*)(gvt + off), (AS3 void*)(smem + 32768 + off), 16, 0, 0);
    }
  }
  asm volatile("s_waitcnt vmcnt(0)" ::: "memory");
  __syncthreads();

  int cur = 0;
  for (int kt = kts; kt <= qt; ++kt) {
    if (kt < qt) {       // prefetch next tile into other buffer (overlaps compute)
      const char* gkt = gk + (size_t)(kt + 1) * 32768;
      const char* gvt = gv + (size_t)(kt + 1) * 32768;
      char* lb = smem + (cur ^ 1) * 65536;
      #pragma unroll
      for (int i = 0; i < 8; ++i) {
        int off = (i * 256 + tid) * 16;
        __builtin_amdgcn_global_load_lds((const AS1 void*)(gkt + off), (AS3 void*)(lb + off), 16, 0, 0);
        __builtin_amdgcn_global_load_lds((const AS1 void*)(gvt + off), (AS3 void*)(lb + 32768 + off), 16, 0, 0);
      }
    }
    const float Gtv = Gt_arr[bh * 16 + kt];
    const float dM = Gtv - Mt;
    if (__any(dM >= -25.f)) {
      const float rf = __expf(dM);
      const char* kb = smem + cur * 65536;
      const char* vb = smem + cur * 65536 + 32768;
      uint4 pfr[8];
      float tsum = 0.f;
      #pragma unroll
      for (int sf = 0; sf < 4; ++sf) {
        f32x16 sacc = {};
        const char* krow = kb + (32 * sf + lo) * 256;
        #pragma unroll
        for (int ks = 0; ks < 8; ++ks) {
          f16x8 a = *(const f16x8*)(krow + ((ks * 32 + hi * 16) ^ swz));
          sacc = __builtin_amdgcn_mfma_f32_32x32x16_f16(a, qf[ks], sacc, 0, 0, 0);
        }
        float vals[16];
        #pragma unroll
        for (int r = 0; r < 16; ++r) {
          float val = sacc[r] * rf;
          if (kt == qt) {
            int sl = 32 * sf + (r & 3) + 8 * (r >> 2) + 4 * hi;
            if (sl > tl) val = 0.f;
          }
          tsum += val;
          vals[r] = val;
        }
        uint32_t a0 = pkh(vals[0], vals[1]),  a1 = pkh(vals[2], vals[3]);
        uint32_t a2 = pkh(vals[4], vals[5]),  a3 = pkh(vals[6], vals[7]);
        uint32_t b0 = pkh(vals[8], vals[9]),  b1 = pkh(vals[10], vals[11]);
        uint32_t b2 = pkh(vals[12], vals[13]), b3 = pkh(vals[14], vals[15]);
        uint32_t sa0 = __shfl_xor(a0, 32), sa1 = __shfl_xor(a1, 32);
        uint32_t sa2 = __shfl_xor(a2, 32), sa3 = __shfl_xor(a3, 32);
        uint32_t sb0 = __shfl_xor(b0, 32), sb1 = __shfl_xor(b1, 32);
        uint32_t sb2 = __shfl_xor(b2, 32), sb3 = __shfl_xor(b3, 32);
        uint4 f0, f1;
        f0.x = hi ? sa2 : a0;  f0.y = hi ? sa3 : a1;
        f0.z = hi ? a2 : sa0;  f0.w = hi ? a3 : sa1;
        f1.x = hi ? sb2 : b0;  f1.y = hi ? sb3 : b1;
        f1.z = hi ? b2 : sb0;  f1.w = hi ? b3 : sb1;
        pfr[2 * sf] = f0; pfr[2 * sf + 1] = f1;
      }
      rowsum += tsum + __shfl_xor(tsum, 32);
      #pragma unroll
      for (int df = 0; df < 4; ++df) {
        const char* vrow = vb + (32 * df + lo) * 256;
        #pragma unroll
        for (int ks = 0; ks < 8; ++ks) {
          f16x8 a = *(const f16x8*)(vrow + ((ks * 32 + hi * 16) ^ swz));
          f16x8 p = __builtin_bit_cast(f16x8, pfr[ks]);
          h[df] = __builtin_amdgcn_mfma_f32_32x32x16_f16(a, p, h[df], 0, 0, 0);
        }
      }
    }
    asm volatile("s_waitcnt vmcnt(0)" ::: "memory");
    __syncthreads();
    cur ^= 1;
  }

  // ---- epilogue: n, LN, store (all in-register; lane pairs via shfl_xor 32) ----
  float n = fmaxf(fabsf(rowsum), em);
  float invn = 1.f / (n + 5e-5f);
  float s1 = 0.f, s2 = 0.f;
  #pragma unroll
  for (int df = 0; df < 4; ++df) {
    #pragma unroll
    for (int r = 0; r < 16; ++r) {
      float x = h[df][r] * invn;
      h[df][r] = x;
      s1 += x; s2 += x * x;
    }
  }
  s1 += __shfl_xor(s1, 32);
  s2 += __shfl_xor(s2, 32);
  float mu = s1 * (1.f / 128.f);
  float var = s2 * (1.f / 128.f) - mu * mu;
  float rstd = rsqrtf(var + 1e-3f);
  float* orow = out + ((size_t)(b * S_LEN) + tg) * D_DIM + hh * DHEAD;
  #pragma unroll
  for (int df = 0; df < 4; ++df) {
    #pragma unroll
    for (int rq = 0; rq < 4; ++rq) {
      int dbase = 32 * df + 8 * rq + 4 * hi;
      float4 wv = *(const float4*)(ln_w + hh * DHEAD + dbase);
      float4 bv = *(const float4*)(ln_b + hh * DHEAD + dbase);
      float4 o;
      o.x = (h[df][rq * 4 + 0] - mu) * rstd * (1.f + wv.x) + bv.x;
      o.y = (h[df][rq * 4 + 1] - mu) * rstd * (1.f + wv.y) + bv.y;
      o.z = (h[df][rq * 4 + 2] - mu) * rstd * (1.f + wv.z) + bv.z;
      o.w = (h[df][rq * 4 + 3] - mu) * rstd * (1.f + wv.w) + bv.w;
      *(float4*)(orow + dbase) = o;
    }
  }
}

extern "C" void kernel_launch(void* const* d_in, const int* in_sizes, int n_in,
                              void* d_out, int out_size, void* d_ws, size_t ws_size,
                              hipStream_t stream) {
  (void)in_sizes; (void)n_in; (void)out_size; (void)ws_size;
  const float* q    = (const float*)d_in[0];
  const float* k    = (const float*)d_in[1];
  const float* v    = (const float*)d_in[2];
  const float* Wi   = (const float*)d_in[3];
  const float* bi   = (const float*)d_in[4];
  const float* Wf   = (const float*)d_in[5];
  const float* bf   = (const float*)d_in[6];
  const float* ln_w = (const float*)d_in[7];
  const float* ln_b = (const float*)d_in[8];

  char* wsb = (char*)d_ws;
  float* ipre = (float*)(wsb + 0);
  float* fpre = (float*)(wsb + 131072);
  float* garr = (float*)(wsb + 262144);
  float* Marr = (float*)(wsb + 393216);
  float* bsum = (float*)(wsb + 524288);
  float* Gt   = (float*)(wsb + 655360);
  char* qh = wsb + 1048576;
  char* kh = wsb + 1048576 + 8388608;
  char* vt = wsb + 1048576 + 16777216;

  gate_kernel<<<2048, 256, 0, stream>>>(q, k, v, Wi, bi, Wf, bf, ipre, fpre);
  scan_kernel<<<16, 256, 0, stream>>>(ipre, fpre, garr, Marr, bsum, Gt);
  convert_kernel<<<dim3(16, 16), 256, 0, stream>>>(q, k, v, garr, Gt, qh, kh, vt);
  attn_kernel<<<dim3(16, 16), 256, 0, stream>>>(qh, kh, vt, Marr, bsum, Gt,
                                                ln_w, ln_b, (float*)d_out);
}

// Round 4
// 97.825 us; speedup vs baseline: 7.2271x; 1.1353x over previous
//
#include <hip/hip_runtime.h>
#include <cstddef>
#include <cstdint>

#define S_LEN 2048
#define D_DIM 512
#define NHEAD 4
#define DHEAD 128
#define BH_CNT 16
#define SCALE_QK 0.08838834764831845f

typedef _Float16 f16;
typedef _Float16 f16x8 __attribute__((ext_vector_type(8)));
typedef float f32x16 __attribute__((ext_vector_type(16)));

#define AS1 __attribute__((address_space(1)))
#define AS3 __attribute__((address_space(3)))

__device__ __forceinline__ unsigned pkh(float a, float b) {
  auto r = __builtin_amdgcn_cvt_pkrtz(a, b);   // __fp16 ext_vector_type(2)
  return __builtin_bit_cast(unsigned, r);
}

// ---------------- Kernel 1: gate preactivations ----------------
__global__ __launch_bounds__(256) void gate_kernel(
    const float* __restrict__ q, const float* __restrict__ k, const float* __restrict__ v,
    const float* __restrict__ Wi, const float* __restrict__ bi,
    const float* __restrict__ Wf, const float* __restrict__ bf,
    float* __restrict__ ipre, float* __restrict__ fpre)
{
  const int wave = threadIdx.x >> 6;
  const int lane = threadIdx.x & 63;
  const int pos  = blockIdx.x * 4 + wave;
  const int b = pos >> 11;
  const int s = pos & 2047;
  const float* qp = q + (size_t)pos * D_DIM;
  const float* kp = k + (size_t)pos * D_DIM;
  const float* vp = v + (size_t)pos * D_DIM;

  float acc[8] = {0.f,0.f,0.f,0.f,0.f,0.f,0.f,0.f};
  #pragma unroll
  for (int j = 0; j < 24; ++j) {
    int e = lane + (j << 6);
    float x;
    if (e < 512)       x = qp[e];
    else if (e < 1024) x = kp[e - 512];
    else               x = vp[e - 1024];
    #pragma unroll
    for (int h = 0; h < 4; ++h) {
      acc[h]     = fmaf(x, Wi[h * 1536 + e], acc[h]);
      acc[4 + h] = fmaf(x, Wf[h * 1536 + e], acc[4 + h]);
    }
  }
  #pragma unroll
  for (int off = 32; off > 0; off >>= 1) {
    #pragma unroll
    for (int a = 0; a < 8; ++a) acc[a] += __shfl_down(acc[a], off);
  }
  if (lane == 0) {
    #pragma unroll
    for (int h = 0; h < 4; ++h) {
      ipre[(size_t)(b * 4 + h) * S_LEN + s] = acc[h] + bi[h];
      fpre[(size_t)(b * 4 + h) * S_LEN + s] = acc[4 + h] + bf[h];
    }
  }
}

// ---------------- Kernel 2: scans + per-64-tile g max ----------------
__global__ __launch_bounds__(256) void scan_kernel(
    const float* __restrict__ ipre, const float* __restrict__ fpre,
    float* __restrict__ g_out, float* __restrict__ M_out,
    float* __restrict__ bsum_out, float* __restrict__ Gt_out)
{
  __shared__ float A[2048];
  __shared__ float Bf[2048];
  const int bh  = blockIdx.x;
  const int tid = threadIdx.x;
  const float* fp = fpre + (size_t)bh * S_LEN;
  const float* ip = ipre + (size_t)bh * S_LEN;

  for (int i = tid; i < 2048; i += 256) {
    float x = fp[i];
    A[i] = fminf(x, 0.f) - log1pf(expf(-fabsf(x)));
  }
  __syncthreads();
  float* src = A; float* dst = Bf;
  for (int off = 1; off < 2048; off <<= 1) {
    for (int i = tid; i < 2048; i += 256)
      dst[i] = (i >= off) ? (src[i] + src[i - off]) : src[i];
    __syncthreads();
    float* t = src; src = dst; dst = t;
  }
  // src = bcum
  for (int i = tid; i < 2048; i += 256) {
    float bs = src[i];
    bsum_out[(size_t)bh * S_LEN + i] = bs;
    float g = ip[i] - bs;
    g_out[(size_t)bh * S_LEN + i] = g;
    dst[i] = g;
  }
  __syncthreads();
  { float* t = src; src = dst; dst = t; }      // src = g
  if (tid < 32) {
    float m = -3.0e38f;
    for (int i = 0; i < 64; ++i) m = fmaxf(m, src[tid * 64 + i]);
    Gt_out[bh * 32 + tid] = m;                 // per-64-row-tile max of g
  }
  __syncthreads();
  for (int off = 1; off < 2048; off <<= 1) {
    for (int i = tid; i < 2048; i += 256)
      dst[i] = (i >= off) ? fmaxf(src[i], src[i - off]) : src[i];
    __syncthreads();
    float* t = src; src = dst; dst = t;
  }
  for (int i = tid; i < 2048; i += 256)
    M_out[(size_t)bh * S_LEN + i] = src[i];
}

// ---------------- Kernel 3: fp16 conversion into MFMA-ready swizzled layouts ----
// qhat/khat tile (bh,it128): row s(128) x 256B, elem d at byte (2d)^((s&15)<<4)
// vT tile (bh,jt64):        row d(128) x 128B, elem s at byte (2s)^((d&15)<<3)
__global__ __launch_bounds__(256) void convert_kernel(
    const float* __restrict__ q, const float* __restrict__ k, const float* __restrict__ v,
    const float* __restrict__ g_arr, const float* __restrict__ Gt_arr,
    char* __restrict__ qhat, char* __restrict__ khat, char* __restrict__ vT)
{
  const int it = blockIdx.x;     // 128-row tile index
  const int bh = blockIdx.y;
  const int b = bh >> 2, hh = bh & 3;
  const int tid = threadIdx.x;
  const size_t tb = (size_t)(bh * 16 + it) * 32768;
  const int rl = tid & 31, rg = tid >> 5;
  for (int j = 0; j < 16; ++j) {
    const int s = rg + 8 * j;
    const int sg = it * 128 + s;
    const float* qrow = q + ((size_t)(b * S_LEN + sg)) * D_DIM + hh * DHEAD;
    const float* krow = k + ((size_t)(b * S_LEN + sg)) * D_DIM + hh * DHEAD;
    float4 qv = *(const float4*)(qrow + rl * 4);
    float4 kv = *(const float4*)(krow + rl * 4);
    float cf = __expf(g_arr[(size_t)bh * S_LEN + sg] - Gt_arr[bh * 32 + (sg >> 6)]);
    uint2 qp, kp;
    qp.x = pkh(qv.x * SCALE_QK, qv.y * SCALE_QK);
    qp.y = pkh(qv.z * SCALE_QK, qv.w * SCALE_QK);
    kp.x = pkh(kv.x * cf, kv.y * cf);
    kp.y = pkh(kv.z * cf, kv.w * cf);
    const int off = (rl * 8) ^ ((s & 15) << 4);
    *(uint2*)(qhat + tb + s * 256 + off) = qp;
    *(uint2*)(khat + tb + s * 256 + off) = kp;
  }
  // V: two 64-row tiles per block
  const int d = tid & 127, oc = tid >> 7;
  const int swz8 = (d & 15) << 3;
  #pragma unroll
  for (int jt = 0; jt < 2; ++jt) {
    const size_t vtb = (size_t)(bh * 32 + it * 2 + jt) * 16384 + (size_t)d * 128;
    for (int j = 0; j < 4; ++j) {
      const int s0 = (oc + 2 * j) * 8;           // 0..56 step 8 (with oc)
      float vv[8];
      #pragma unroll
      for (int i = 0; i < 8; ++i)
        vv[i] = v[((size_t)(b * S_LEN + it * 128 + jt * 64 + s0 + i)) * D_DIM + hh * DHEAD + d];
      uint2 p0, p1;
      p0.x = pkh(vv[0], vv[1]); p0.y = pkh(vv[2], vv[3]);
      p1.x = pkh(vv[4], vv[5]); p1.y = pkh(vv[6], vv[7]);
      *(uint2*)(vT + vtb + ((2 * s0) ^ swz8))     = p0;
      *(uint2*)(vT + vtb + ((2 * s0 + 8) ^ swz8)) = p1;
    }
  }
}

// ---------------- Kernel 4: MFMA attention ----------------
// q-tile 64 rows, kt-tiles 64. 4 waves: (t-half = w&1, s-half = w>>1).
// S = K_hat * Qhat^T (32s x 32t per wave), P -> PV B-frags in-register,
// h^T(128d x 32t) accumulated per wave over its s-half; s-halves combined
// via LDS at the end; then n, LN, store.
__global__ __launch_bounds__(256, 2) void attn_kernel(
    const char* __restrict__ qhat, const char* __restrict__ khat, const char* __restrict__ vT,
    const float* __restrict__ M_arr, const float* __restrict__ bs_arr,
    const float* __restrict__ Gt_arr,
    const float* __restrict__ ln_w, const float* __restrict__ ln_b,
    float* __restrict__ out)
{
  __shared__ __align__(16) char smem[65536];   // buf p at p*32768: K 16K + V 16K
  const int j  = 31 - (int)blockIdx.x;         // heavy tiles first
  const int bh = blockIdx.y;
  const int b = bh >> 2, hh = bh & 3;
  const int tid = threadIdx.x;
  const int w = tid >> 6, lane = tid & 63, lo = lane & 31, hi = lane >> 5;
  const int th = w & 1, sh = w >> 1;
  const int tl = th * 32 + lo;           // local t (0..63)
  const int tg = j * 64 + tl;            // global t
  const int swzq = (tl & 15) << 4;
  const int swzk = (lo & 15) << 4;

  const char* gq = qhat + (size_t)bh * 524288 + (size_t)j * 16384;
  const char* gk = khat + (size_t)bh * 524288;
  const char* gv = vT   + (size_t)bh * 524288;

  const float Mt = M_arr[(size_t)bh * S_LEN + tg];
  const float em = __expf(-(bs_arr[(size_t)bh * S_LEN + tg] + Mt));
  const float M0 = M_arr[(size_t)bh * S_LEN + j * 64];

  int kts = 0;
  while (kts < j && Gt_arr[bh * 32 + kts] < M0 - 25.f) ++kts;

  // stage Q sub-tile (16 KB) into buf1, read fragments into regs
  #pragma unroll
  for (int i = 0; i < 4; ++i) {
    int off = (i * 256 + tid) * 16;
    __builtin_amdgcn_global_load_lds((const AS1 void*)(gq + off),
                                     (AS3 void*)(smem + 32768 + off), 16, 0, 0);
  }
  asm volatile("s_waitcnt vmcnt(0)" ::: "memory");
  __syncthreads();
  f16x8 qf[8];
  #pragma unroll
  for (int ks = 0; ks < 8; ++ks)
    qf[ks] = *(const f16x8*)(smem + 32768 + tl * 256 + ((ks * 32 + hi * 16) ^ swzq));
  __syncthreads();

  f32x16 h[4] = {{}, {}, {}, {}};
  float rowsum = 0.f;

  // prologue: stage tile kts into buf0
  {
    const char* gkt = gk + (size_t)kts * 16384;
    const char* gvt = gv + (size_t)kts * 16384;
    #pragma unroll
    for (int i = 0; i < 4; ++i) {
      int off = (i * 256 + tid) * 16;
      __builtin_amdgcn_global_load_lds((const AS1 void*)(gkt + off), (AS3 void*)(smem + off), 16, 0, 0);
      __builtin_amdgcn_global_load_lds((const AS1 void*)(gvt + off), (AS3 void*)(smem + 16384 + off), 16, 0, 0);
    }
  }
  asm volatile("s_waitcnt vmcnt(0)" ::: "memory");
  __syncthreads();

  int cur = 0;
  for (int kt = kts; kt <= j; ++kt) {
    if (kt < j) {       // prefetch next tile into other buffer
      const char* gkt = gk + (size_t)(kt + 1) * 16384;
      const char* gvt = gv + (size_t)(kt + 1) * 16384;
      char* lb = smem + (cur ^ 1) * 32768;
      #pragma unroll
      for (int i = 0; i < 4; ++i) {
        int off = (i * 256 + tid) * 16;
        __builtin_amdgcn_global_load_lds((const AS1 void*)(gkt + off), (AS3 void*)(lb + off), 16, 0, 0);
        __builtin_amdgcn_global_load_lds((const AS1 void*)(gvt + off), (AS3 void*)(lb + 16384 + off), 16, 0, 0);
      }
    }
    const float dM = Gt_arr[bh * 32 + kt] - Mt;
    if (__any(dM >= -25.f)) {
      const float rf = __expf(dM);
      const char* kb  = smem + cur * 32768;
      const char* vbp = smem + cur * 32768 + 16384;
      // ---- QK^T: wave's 32-s block x 32-t block ----
      f32x16 sacc = {};
      const char* krow = kb + (32 * sh + lo) * 256;
      #pragma unroll
      for (int ks = 0; ks < 8; ++ks) {
        f16x8 a = *(const f16x8*)(krow + ((ks * 32 + hi * 16) ^ swzk));
        sacc = __builtin_amdgcn_mfma_f32_32x32x16_f16(a, qf[ks], sacc, 0, 0, 0);
      }
      float vals[16];
      float tsum = 0.f;
      #pragma unroll
      for (int r = 0; r < 16; ++r) {
        float val = sacc[r] * rf;
        if (kt == j) {
          int sl = 32 * sh + (r & 3) + 8 * (r >> 2) + 4 * hi;
          if (sl > tl) val = 0.f;
        }
        tsum += val;
        vals[r] = val;
      }
      rowsum += tsum + __shfl_xor(tsum, 32);
      uint32_t a0 = pkh(vals[0], vals[1]),  a1 = pkh(vals[2], vals[3]);
      uint32_t a2 = pkh(vals[4], vals[5]),  a3 = pkh(vals[6], vals[7]);
      uint32_t b0 = pkh(vals[8], vals[9]),  b1 = pkh(vals[10], vals[11]);
      uint32_t b2 = pkh(vals[12], vals[13]), b3 = pkh(vals[14], vals[15]);
      uint32_t sa0 = __shfl_xor(a0, 32), sa1 = __shfl_xor(a1, 32);
      uint32_t sa2 = __shfl_xor(a2, 32), sa3 = __shfl_xor(a3, 32);
      uint32_t sb0 = __shfl_xor(b0, 32), sb1 = __shfl_xor(b1, 32);
      uint32_t sb2 = __shfl_xor(b2, 32), sb3 = __shfl_xor(b3, 32);
      uint4 f0, f1;
      f0.x = hi ? sa2 : a0;  f0.y = hi ? sa3 : a1;
      f0.z = hi ? a2 : sa0;  f0.w = hi ? a3 : sa1;
      f1.x = hi ? sb2 : b0;  f1.y = hi ? sb3 : b1;
      f1.z = hi ? b2 : sb0;  f1.w = hi ? b3 : sb1;
      // ---- PV: 4 d-blocks x 2 ks over wave's 32-s block ----
      #pragma unroll
      for (int df = 0; df < 4; ++df) {
        const int d = 32 * df + lo;
        const char* vrow = vbp + d * 128;
        const int swzv = (d & 15) << 3;
        #pragma unroll
        for (int ks2 = 0; ks2 < 2; ++ks2) {
          const int x = sh * 64 + ks2 * 32 + hi * 16;
          uint2 p0 = *(const uint2*)(vrow + ((x) ^ swzv));
          uint2 p1 = *(const uint2*)(vrow + ((x + 8) ^ swzv));
          uint4 av; av.x = p0.x; av.y = p0.y; av.z = p1.x; av.w = p1.y;
          f16x8 a = __builtin_bit_cast(f16x8, av);
          f16x8 p = __builtin_bit_cast(f16x8, ks2 ? f1 : f0);
          h[df] = __builtin_amdgcn_mfma_f32_32x32x16_f16(a, p, h[df], 0, 0, 0);
        }
      }
    }
    asm volatile("s_waitcnt vmcnt(0)" ::: "memory");
    __syncthreads();
    cur ^= 1;
  }

  // ---- combine s-halves via LDS (reuse K/V buffers) ----
  float* cb = (float*)smem;
  if (sh == 1) {
    #pragma unroll
    for (int df = 0; df < 4; ++df)
      #pragma unroll
      for (int r = 0; r < 16; ++r)
        cb[(th * 4096 + df * 1024 + r * 64 + lane)] = h[df][r];
    cb[8192 + th * 64 + lane] = rowsum;
  }
  __syncthreads();
  if (sh == 1) return;
  #pragma unroll
  for (int df = 0; df < 4; ++df)
    #pragma unroll
    for (int r = 0; r < 16; ++r)
      h[df][r] += cb[(th * 4096 + df * 1024 + r * 64 + lane)];
  rowsum += cb[8192 + th * 64 + lane];

  // ---- epilogue: n, LN, store ----
  float n = fmaxf(fabsf(rowsum), em);
  float invn = 1.f / (n + 5e-5f);
  float s1 = 0.f, s2 = 0.f;
  #pragma unroll
  for (int df = 0; df < 4; ++df) {
    #pragma unroll
    for (int r = 0; r < 16; ++r) {
      float x = h[df][r] * invn;
      h[df][r] = x;
      s1 += x; s2 += x * x;
    }
  }
  s1 += __shfl_xor(s1, 32);
  s2 += __shfl_xor(s2, 32);
  float mu = s1 * (1.f / 128.f);
  float var = s2 * (1.f / 128.f) - mu * mu;
  float rstd = rsqrtf(var + 1e-3f);
  float* orow = out + ((size_t)(b * S_LEN) + tg) * D_DIM + hh * DHEAD;
  #pragma unroll
  for (int df = 0; df < 4; ++df) {
    #pragma unroll
    for (int rq = 0; rq < 4; ++rq) {
      int dbase = 32 * df + 8 * rq + 4 * hi;
      float4 wv = *(const float4*)(ln_w + hh * DHEAD + dbase);
      float4 bv = *(const float4*)(ln_b + hh * DHEAD + dbase);
      float4 o;
      o.x = (h[df][rq * 4 + 0] - mu) * rstd * (1.f + wv.x) + bv.x;
      o.y = (h[df][rq * 4 + 1] - mu) * rstd * (1.f + wv.y) + bv.y;
      o.z = (h[df][rq * 4 + 2] - mu) * rstd * (1.f + wv.z) + bv.z;
      o.w = (h[df][rq * 4 + 3] - mu) * rstd * (1.f + wv.w) + bv.w;
      *(float4*)(orow + dbase) = o;
    }
  }
}

extern "C" void kernel_launch(void* const* d_in, const int* in_sizes, int n_in,
                              void* d_out, int out_size, void* d_ws, size_t ws_size,
                              hipStream_t stream) {
  (void)in_sizes; (void)n_in; (void)out_size; (void)ws_size;
  const float* q    = (const float*)d_in[0];
  const float* k    = (const float*)d_in[1];
  const float* v    = (const float*)d_in[2];
  const float* Wi   = (const float*)d_in[3];
  const float* bi   = (const float*)d_in[4];
  const float* Wf   = (const float*)d_in[5];
  const float* bf   = (const float*)d_in[6];
  const float* ln_w = (const float*)d_in[7];
  const float* ln_b = (const float*)d_in[8];

  char* wsb = (char*)d_ws;
  float* ipre = (float*)(wsb + 0);
  float* fpre = (float*)(wsb + 131072);
  float* garr = (float*)(wsb + 262144);
  float* Marr = (float*)(wsb + 393216);
  float* bsum = (float*)(wsb + 524288);
  float* Gt   = (float*)(wsb + 655360);       // 16*32 floats
  char* qh = wsb + 1048576;
  char* kh = wsb + 1048576 + 8388608;
  char* vt = wsb + 1048576 + 16777216;

  gate_kernel<<<2048, 256, 0, stream>>>(q, k, v, Wi, bi, Wf, bf, ipre, fpre);
  scan_kernel<<<16, 256, 0, stream>>>(ipre, fpre, garr, Marr, bsum, Gt);
  convert_kernel<<<dim3(16, 16), 256, 0, stream>>>(q, k, v, garr, Gt, qh, kh, vt);
  attn_kernel<<<dim3(32, 16), 256, 0, stream>>>(qh, kh, vt, Marr, bsum, Gt,
                                                ln_w, ln_b, (float*)d_out);
}